// Round 16
// baseline (75.646 us; speedup 1.0000x reference)
//
#include <hip/hip_runtime.h>

#define BSZ 4096
#define D 1024
#define N2 8192
#define TEMPV 0.5f
// exp(x/T) = exp2(x * log2(e)/T)
#define EXPSCALE 2.8853900817779268f
#define NTB2 64     // 8192 / 128 tiles per dim

typedef __attribute__((ext_vector_type(4))) float f32x4;
typedef __attribute__((ext_vector_type(4))) int i32x4;
typedef __attribute__((ext_vector_type(8))) int i32x8;

// bit-exact float -> OCP e4m3fn, RNE (inputs |x|<=1 here; clamp kept for safety)
__device__ inline unsigned int f2e4m3(float x) {
  unsigned int u = __float_as_uint(x);
  const unsigned int s = (u >> 24) & 0x80u;
  u &= 0x7fffffffu;
  const float a = __uint_as_float(u);
  if (a >= 448.0f) return s | 0x7Eu;
  if (a < 0.015625f) {                       // < 2^-6: subnormal
    const int m = (int)rintf(a * 512.0f);    // RNE; 8 -> 0x08 == 2^-6 exactly
    return s | (unsigned int)m;
  }
  u += 0x7FFFFu + ((u >> 20) & 1u);          // RNE to 3 mantissa bits
  const unsigned int e = u >> 23;            // biased f32 exp (>=121)
  const unsigned int m3 = (u >> 20) & 7u;
  return s | (((e - 120u) << 3) | m3);       // e4m3 bias 7
}

__device__ inline void gload16(const void* g, void* l) {
  __builtin_amdgcn_global_load_lds(
      (const __attribute__((address_space(1))) void*)g,
      (__attribute__((address_space(3))) void*)l, 16, 0, 0);
}

// ---------------- Kernel A: L2-normalize rows, emit fp8 reps + pos dot ------------------
__global__ __launch_bounds__(256) void knorm(const float* __restrict__ ei,
                                             const float* __restrict__ ej,
                                             unsigned char* __restrict__ reps8,
                                             float* __restrict__ pos) {
  const int r = blockIdx.x;
  const int t = threadIdx.x;
  const float4 vi = ((const float4*)(ei + (size_t)r * D))[t];
  const float4 vj = ((const float4*)(ej + (size_t)r * D))[t];
  float ssi = vi.x * vi.x + vi.y * vi.y + vi.z * vi.z + vi.w * vi.w;
  float ssj = vj.x * vj.x + vj.y * vj.y + vj.z * vj.z + vj.w * vj.w;
  float sij = vi.x * vj.x + vi.y * vj.y + vi.z * vj.z + vi.w * vj.w;
#pragma unroll
  for (int o = 32; o > 0; o >>= 1) {
    ssi += __shfl_xor(ssi, o);
    ssj += __shfl_xor(ssj, o);
    sij += __shfl_xor(sij, o);
  }
  __shared__ float red[12];
  const int lane = t & 63, wid = t >> 6;
  if (lane == 0) { red[wid * 3] = ssi; red[wid * 3 + 1] = ssj; red[wid * 3 + 2] = sij; }
  __syncthreads();
  ssi = red[0] + red[3] + red[6] + red[9];
  ssj = red[1] + red[4] + red[7] + red[10];
  sij = red[2] + red[5] + red[8] + red[11];
  const float inv_i = rsqrtf(fmaxf(ssi, 1e-24f));
  const float inv_j = rsqrtf(fmaxf(ssj, 1e-24f));
  const float xi0 = vi.x * inv_i, xi1 = vi.y * inv_i, xi2 = vi.z * inv_i, xi3 = vi.w * inv_i;
  const float xj0 = vj.x * inv_j, xj1 = vj.y * inv_j, xj2 = vj.z * inv_j, xj3 = vj.w * inv_j;
  const unsigned int pi = f2e4m3(xi0) | (f2e4m3(xi1) << 8) | (f2e4m3(xi2) << 16) | (f2e4m3(xi3) << 24);
  const unsigned int pj = f2e4m3(xj0) | (f2e4m3(xj1) << 8) | (f2e4m3(xj2) << 16) | (f2e4m3(xj3) << 24);
  *(unsigned int*)(reps8 + (size_t)r * 1024 + t * 4) = pi;
  *(unsigned int*)(reps8 + (size_t)(BSZ + r) * 1024 + t * 4) = pj;
  if (t == 0) pos[r] = sij * inv_i * inv_j;
}

// ======================= shared asm helpers =======================
#define BARRIER() do { __builtin_amdgcn_s_barrier(); asm volatile("" ::: "memory"); } while (0)
#define STR2(x) #x
#define WAITV(n) asm volatile("s_waitcnt vmcnt(" STR2(n) ")" ::: "memory")

// ---------------- Kernel B: 2080 upper-triangle 128x128 MX-fp8 tiles --------------------
// 4 waves (2x2 grid), wave tile 64x64 (acc[4][4]=64 VGPR), BK=128, LDS 64 KiB
// (A dbuf @0/@16384, B dbuf @32768/@49152) -> 2 blocks/CU co-resident: the partner
// block's waves cover this block's vmcnt(0)/barrier stalls (m114 overlap).
// Per tile: 16 MFMA consume frags read at END of previous tile (zero-lgkm MFMA
// region); stage A(t+1)/B(t+1) interleaved with MFMA; 2 barriers + vmcnt(0)/tile.
// Swizzle: LDS[row][c16] = orig[row][c16 ^ (row&7)]; read off = (2q2+b ^ r7)<<4.
#define SG_A4(ktv, dst)                                                               \
  { _Pragma("unroll") for (int ii_ = 0; ii_ < 4; ii_++)                               \
      gload16(reps8 + (size_t)(arow0 + ii_ * 32 + (t >> 3)) * 1024 +                  \
                  (ktv) * 128 + (((t & 7) ^ ((t >> 3) & 7)) << 4),                    \
              (dst) + (size_t)ii_ * 4096 + (size_t)t * 16); }
#define SG_B4(ktv, dst)                                                               \
  { _Pragma("unroll") for (int ii_ = 0; ii_ < 4; ii_++)                               \
      gload16(reps8 + (size_t)(brow0 + ii_ * 32 + (t >> 3)) * 1024 +                  \
                  (ktv) * 128 + (((t & 7) ^ ((t >> 3) & 7)) << 4),                    \
              (dst) + (size_t)ii_ * 4096 + (size_t)t * 16); }

#define ABUF(c) ((c) ? 16384 : 0)
#define BBUF(c) ((c) ? 49152 : 32768)

#define READ_ALL(par) do {                                                            \
    _Pragma("unroll") for (int n_ = 0; n_ < 4; n_++) {                                \
      i32x4 lo_ = *(const i32x4*)(smem + BBUF(par) + (brow + n_ * 16) * 128 + off0);  \
      i32x4 hi_ = *(const i32x4*)(smem + BBUF(par) + (brow + n_ * 16) * 128 + off1);  \
      bfp[n_] = __builtin_shufflevector(lo_, hi_, 0, 1, 2, 3, 4, 5, 6, 7);            \
    }                                                                                 \
    _Pragma("unroll") for (int m_ = 0; m_ < 4; m_++) {                                \
      i32x4 lo_ = *(const i32x4*)(smem + ABUF(par) + (arow + m_ * 16) * 128 + off0);  \
      i32x4 hi_ = *(const i32x4*)(smem + ABUF(par) + (arow + m_ * 16) * 128 + off1);  \
      afp[m_] = __builtin_shufflevector(lo_, hi_, 0, 1, 2, 3, 4, 5, 6, 7);            \
    }                                                                                 \
  } while (0)

#define MFMA_M(m)                                                       \
  __builtin_amdgcn_s_setprio(1);                                        \
  _Pragma("unroll") for (int n_ = 0; n_ < 4; n_++)                      \
    acc[m][n_] = __builtin_amdgcn_mfma_scale_f32_16x16x128_f8f6f4(      \
        afp[m], bfp[n_], acc[m][n_], 0, 0, 0, 0x7F7F7F7F, 0, 0x7F7F7F7F); \
  __builtin_amdgcn_s_setprio(0);

#define DO_TILE(ktv, STG, RDN)                                          \
  {                                                                     \
    if (STG) SG_A4((ktv) + 1, smem + ABUF(!((ktv) & 1)));               \
    MFMA_M(0); MFMA_M(1);                                               \
    if (STG) SG_B4((ktv) + 1, smem + BBUF(!((ktv) & 1)));               \
    MFMA_M(2); MFMA_M(3);                                               \
    if (STG) {                                                          \
      BARRIER();                                                        \
      WAITV(0);                                                         \
      BARRIER();                                                        \
    }                                                                   \
    if (RDN) READ_ALL(!((ktv) & 1));                                    \
  }

__global__ __launch_bounds__(256, 2) void kgemm3(const unsigned char* __restrict__ reps8,
                                                 float* __restrict__ partial) {
  extern __shared__ char smem[];
  const int t = threadIdx.x;
  const int l = t & 63, w = t >> 6;
  const int wr = w >> 1, wc = w & 1;          // 2 x 2 wave grid

  // XCD swizzle (2080 = 8 * 260, bijective), then triangle decode (128-granule).
  int bid = (int)blockIdx.x;
  bid = (bid & 7) * 260 + (bid >> 3);
  int rem = bid;
  int rb = 0;
  while (rem >= NTB2 - rb) { rem -= NTB2 - rb; rb++; }
  const int cb = rb + rem;

  f32x4 acc[4][4];
  const f32x4 zero4 = {0.f, 0.f, 0.f, 0.f};
#pragma unroll
  for (int m = 0; m < 4; m++)
#pragma unroll
    for (int n = 0; n < 4; n++) acc[m][n] = zero4;

  const size_t arow0 = (size_t)rb * 128;
  const size_t brow0 = (size_t)cb * 128;

  // read-side: lane q-group holds orig chunks {2q, 2q+1}; LDS pos = chunk ^ (row&7)
  const int q2 = (l >> 4) & 3;
  const int arow = wr * 64 + (l & 15);
  const int brow = wc * 64 + (l & 15);
  const int r7 = l & 7;                       // == arow&7 == brow&7
  const int off0 = ((2 * q2) ^ r7) << 4;
  const int off1 = ((2 * q2 + 1) ^ r7) << 4;

  // ---- prologue: stage tile 0; drain; read all 8 frags ----
  SG_A4(0, smem);
  SG_B4(0, smem + 32768);
  WAITV(0);
  BARRIER();

  i32x8 afp[4], bfp[4];
  READ_ALL(0);

  DO_TILE(0, 1, 1)
  DO_TILE(1, 1, 1)
  DO_TILE(2, 1, 1)
  DO_TILE(3, 1, 1)
  DO_TILE(4, 1, 1)
  DO_TILE(5, 1, 1)
  DO_TILE(6, 1, 1)
  DO_TILE(7, 0, 0)

  // -------- epilogue: exp + diagonal mask + row/col partial sums --------
  float rsum[4][4];
  float csum[4];
#pragma unroll
  for (int m = 0; m < 4; m++)
#pragma unroll
    for (int j = 0; j < 4; j++) rsum[m][j] = 0.f;
#pragma unroll
  for (int n = 0; n < 4; n++) csum[n] = 0.f;

  const int col16 = l & 15, rgp = (l >> 4) & 3;
  const bool diag = (rb == cb);
  const int growbase = wr * 64 + rgp * 4;     // + m*16 + j (within tile)
  const int gcolbase = wc * 64 + col16;       // + n*16    (within tile)
#pragma unroll
  for (int m = 0; m < 4; m++) {
#pragma unroll
    for (int n = 0; n < 4; n++) {
#pragma unroll
      for (int j = 0; j < 4; j++) {
        const float e = (diag && (growbase + m * 16 + j) == (gcolbase + n * 16))
                            ? 0.f
                            : exp2f(acc[m][n][j] * EXPSCALE);
        rsum[m][j] += e;
        csum[n] += e;
      }
    }
  }
#pragma unroll
  for (int m = 0; m < 4; m++)
#pragma unroll
    for (int j = 0; j < 4; j++) {
      float v = rsum[m][j];
      v += __shfl_xor(v, 1); v += __shfl_xor(v, 2);
      v += __shfl_xor(v, 4); v += __shfl_xor(v, 8);
      rsum[m][j] = v;
    }
#pragma unroll
  for (int n = 0; n < 4; n++) {
    float v = csum[n];
    v += __shfl_xor(v, 16); v += __shfl_xor(v, 32);
    csum[n] = v;
  }

  __syncthreads();   // all waves past their last LDS reads before reuse
  float* rS = (float*)smem;            // [2 wc][128 rows]
  float* cS = ((float*)smem) + 256;    // [2 wr][128 cols]
  if (col16 == 0) {
#pragma unroll
    for (int m = 0; m < 4; m++)
#pragma unroll
      for (int j = 0; j < 4; j++)
        rS[wc * 128 + wr * 64 + m * 16 + rgp * 4 + j] = rsum[m][j];
  }
  if (rgp == 0) {
#pragma unroll
    for (int n = 0; n < 4; n++)
      cS[wr * 128 + wc * 64 + n * 16 + col16] = csum[n];
  }
  __syncthreads();
  // partial layout: [64 col-blocks of 128][8192 rows]
  if (t < 128) {
    const float rs = rS[t] + rS[128 + t];
    partial[(size_t)cb * N2 + rb * 128 + t] = rs;
    if (!diag) {
      const float cs = cS[t] + cS[128 + t];
      partial[(size_t)rb * N2 + cb * 128 + t] = cs;
    }
  }
}

// ---------------- Kernel C1: per-row denom; log; block sum --------------------------------
__device__ inline float blockReduce(float v, float* sred) {
#pragma unroll
  for (int o = 32; o > 0; o >>= 1) v += __shfl_xor(v, o);
  const int lane = threadIdx.x & 63, wid = threadIdx.x >> 6;
  if (lane == 0) sred[wid] = v;
  __syncthreads();
  v = sred[0] + sred[1] + sred[2] + sred[3];
  __syncthreads();
  return v;
}

__global__ __launch_bounds__(256) void kred1(const float* __restrict__ partial,
                                             float* __restrict__ bsum) {
  const int r = blockIdx.x * 256 + threadIdx.x;
  float d = 0.f;
#pragma unroll 8
  for (int cbx = 0; cbx < 64; ++cbx) d += partial[(size_t)cbx * N2 + r];
  float v = logf(d);
  __shared__ float sred[4];
  v = blockReduce(v, sred);
  if (threadIdx.x == 0) bsum[blockIdx.x] = v;
}

// ---------------- Kernel C2: final scalar -------------------------------------------------
__global__ __launch_bounds__(256) void kred2(const float* __restrict__ bsum,
                                             const float* __restrict__ pos,
                                             float* __restrict__ out) {
  const int t = threadIdx.x;
  float v = (t < 32) ? bsum[t] : 0.f;
  float p = 0.f;
  for (int k = t; k < BSZ; k += 256) p += pos[k];
  __shared__ float sred[4];
  v = blockReduce(v, sred);
  p = blockReduce(p, sred);
  if (t == 0) out[0] = (v - 2.0f * p / TEMPV) / (float)N2;
}

extern "C" void kernel_launch(void* const* d_in, const int* in_sizes, int n_in,
                              void* d_out, int out_size, void* d_ws, size_t ws_size,
                              hipStream_t stream) {
  const float* ei = (const float*)d_in[0];
  const float* ej = (const float*)d_in[1];
  char* ws = (char*)d_ws;
  unsigned char* reps8 = (unsigned char*)ws;                           // 8 MB fp8 [8192][1024]
  float* partial = (float*)(ws + (size_t)8 * 1024 * 1024);             // 2 MB [64][8192]
  float* pos = (float*)(ws + (size_t)8 * 1024 * 1024 + 2048 * 1024);   // 16 KB [4096]
  float* bsum = (float*)(ws + (size_t)8 * 1024 * 1024 + 2048 * 1024 + 16384); // 128 B

  (void)hipFuncSetAttribute((const void*)kgemm3,
                            hipFuncAttributeMaxDynamicSharedMemorySize, 65536);

  knorm<<<BSZ, 256, 0, stream>>>(ei, ej, reps8, pos);
  kgemm3<<<2080, 256, 65536, stream>>>(reps8, partial);
  kred1<<<32, 256, 0, stream>>>(partial, bsum);
  kred2<<<1, 256, 0, stream>>>(bsum, pos, (float*)d_out);
}

// Round 17
// 68.565 us; speedup vs baseline: 1.1033x; 1.1033x over previous
//
#include <hip/hip_runtime.h>

#define BSZ 4096
#define D 1024
#define N2 8192
#define TEMPV 0.5f
// exp(x/T) = exp2(x * log2(e)/T)
#define EXPSCALE 2.8853900817779268f
#define NTB 32      // 8192 / 256 tiles per dim

typedef __attribute__((ext_vector_type(4))) float f32x4;
typedef __attribute__((ext_vector_type(4))) int i32x4;
typedef __attribute__((ext_vector_type(8))) int i32x8;

// bit-exact float -> OCP e4m3fn, RNE (inputs |x|<=1 here; clamp kept for safety)
__device__ inline unsigned int f2e4m3(float x) {
  unsigned int u = __float_as_uint(x);
  const unsigned int s = (u >> 24) & 0x80u;
  u &= 0x7fffffffu;
  const float a = __uint_as_float(u);
  if (a >= 448.0f) return s | 0x7Eu;
  if (a < 0.015625f) {                       // < 2^-6: subnormal
    const int m = (int)rintf(a * 512.0f);    // RNE; 8 -> 0x08 == 2^-6 exactly
    return s | (unsigned int)m;
  }
  u += 0x7FFFFu + ((u >> 20) & 1u);          // RNE to 3 mantissa bits
  const unsigned int e = u >> 23;            // biased f32 exp (>=121)
  const unsigned int m3 = (u >> 20) & 7u;
  return s | (((e - 120u) << 3) | m3);       // e4m3 bias 7
}

__device__ inline unsigned int pack8(float4 v, float s) {
  return f2e4m3(v.x * s) | (f2e4m3(v.y * s) << 8) |
         (f2e4m3(v.z * s) << 16) | (f2e4m3(v.w * s) << 24);
}

__device__ inline void gload16(const void* g, void* l) {
  __builtin_amdgcn_global_load_lds(
      (const __attribute__((address_space(1))) void*)g,
      (__attribute__((address_space(3))) void*)l, 16, 0, 0);
}

// ---------------- Kernel A: L2-normalize (wave-per-row), emit fp8 reps + pos ------------
// 4 waves/block, 1 row per wave; stride-64 float4 loads; pure-shfl reduction (no LDS).
__global__ __launch_bounds__(256) void knorm(const float* __restrict__ ei,
                                             const float* __restrict__ ej,
                                             unsigned char* __restrict__ reps8,
                                             float* __restrict__ pos) {
  const int w = threadIdx.x >> 6, l = threadIdx.x & 63;
  const int r = blockIdx.x * 4 + w;
  const float4* pi4 = (const float4*)(ei + (size_t)r * D);
  const float4* pj4 = (const float4*)(ej + (size_t)r * D);
  float4 vi[4], vj[4];
  float ssi = 0.f, ssj = 0.f, sij = 0.f;
#pragma unroll
  for (int k = 0; k < 4; k++) {
    vi[k] = pi4[l + 64 * k];
    vj[k] = pj4[l + 64 * k];
    ssi += vi[k].x * vi[k].x + vi[k].y * vi[k].y + vi[k].z * vi[k].z + vi[k].w * vi[k].w;
    ssj += vj[k].x * vj[k].x + vj[k].y * vj[k].y + vj[k].z * vj[k].z + vj[k].w * vj[k].w;
    sij += vi[k].x * vj[k].x + vi[k].y * vj[k].y + vi[k].z * vj[k].z + vi[k].w * vj[k].w;
  }
#pragma unroll
  for (int o = 32; o > 0; o >>= 1) {
    ssi += __shfl_xor(ssi, o);
    ssj += __shfl_xor(ssj, o);
    sij += __shfl_xor(sij, o);
  }
  const float inv_i = rsqrtf(fmaxf(ssi, 1e-24f));
  const float inv_j = rsqrtf(fmaxf(ssj, 1e-24f));
  unsigned int* di = (unsigned int*)(reps8 + (size_t)r * 1024);
  unsigned int* dj = (unsigned int*)(reps8 + (size_t)(BSZ + r) * 1024);
#pragma unroll
  for (int k = 0; k < 4; k++) {
    di[l + 64 * k] = pack8(vi[k], inv_i);
    dj[l + 64 * k] = pack8(vj[k], inv_j);
  }
  if (l == 0) pos[r] = sij * inv_i * inv_j;
}

// ======================= shared asm helpers =======================
#define BARRIER() do { __builtin_amdgcn_s_barrier(); asm volatile("" ::: "memory"); } while (0)
#define STR2(x) #x
#define WAITV(n) asm volatile("s_waitcnt vmcnt(" STR2(n) ")" ::: "memory")
#define LGKM0() asm volatile("s_waitcnt lgkmcnt(0)" ::: "memory")

// ---------------- Kernel B (merged): tails FIRST (0..127), mains (128..639) -------------
// Main: 256x256 MX-fp8 tile (unit scales), BK=128, 8 waves (2Mx4N), wave tile 128x64,
// LDS 128 KiB (A dbuf @0/@16384, B dbuf @32768/@49152), fully unrolled 8 K-tiles.
// BARRIER THINNING (R17): only 2 load-bearing barriers/tile —
//   ph1-end: all waves' current-B reads (bfp[2..3]) done before any wave's ph3 SG_B
//            overwrites the current B buffer;
//   ph3-end: WAITV(4) + visibility so ph4 can read next-tile buffers.
// (ph2-end / tile-end barriers were read-after-read only; removed. Cross-tile hazards
//  are covered transitively by the NEXT tile's ph1-end barrier.)
#define SG_A(ii, ktv, dst) gload16(reps8 + (size_t)(arow0 + (ii) * 64 + (t >> 3)) * 1024 + \
                                       (ktv) * 128 + (((t & 7) ^ ((t >> 3) & 7)) << 4),    \
                                   (dst) + (size_t)(ii) * 8192 + (size_t)t * 16)
#define SG_B(ii, ktv, dst) gload16(reps8 + (size_t)(brow0 + (ii) * 64 + (t >> 3)) * 1024 + \
                                       (ktv) * 128 + (((t & 7) ^ ((t >> 3) & 7)) << 4),    \
                                   (dst) + (size_t)(ii) * 8192 + (size_t)t * 16)

#define ABUF(c) ((c) ? 16384 : 0)
#define BBUF(c) ((c) ? 49152 : 32768)

#define READ_A2(bufoff, p) do {                                                       \
    i32x4 a0l = *(const i32x4*)(smem + (bufoff) + ((p) * 2) * 2048 + aaddr0);         \
    i32x4 a0h = *(const i32x4*)(smem + (bufoff) + ((p) * 2) * 2048 + aaddr1);         \
    i32x4 a1l = *(const i32x4*)(smem + (bufoff) + ((p) * 2 + 1) * 2048 + aaddr0);     \
    i32x4 a1h = *(const i32x4*)(smem + (bufoff) + ((p) * 2 + 1) * 2048 + aaddr1);     \
    afp[0] = __builtin_shufflevector(a0l, a0h, 0, 1, 2, 3, 4, 5, 6, 7);               \
    afp[1] = __builtin_shufflevector(a1l, a1h, 0, 1, 2, 3, 4, 5, 6, 7);               \
  } while (0)

#define READ_B2(bufoff, n) do {                                                       \
    i32x4 bl = *(const i32x4*)(smem + (bufoff) + (n) * 2048 + baddr0);                \
    i32x4 bh = *(const i32x4*)(smem + (bufoff) + (n) * 2048 + baddr1);                \
    bfp[n] = __builtin_shufflevector(bl, bh, 0, 1, 2, 3, 4, 5, 6, 7);                 \
  } while (0)

#define MFMA_P(p)                                                       \
  __builtin_amdgcn_s_setprio(1);                                        \
  _Pragma("unroll") for (int nh = 0; nh < 2; nh++)                      \
  _Pragma("unroll") for (int m2 = 0; m2 < 2; m2++)                      \
  _Pragma("unroll") for (int nn = 0; nn < 2; nn++) {                    \
    const int n_ = nh * 2 + nn;                                         \
    acc[2 * (p) + m2][n_] = __builtin_amdgcn_mfma_scale_f32_16x16x128_f8f6f4( \
        afp[m2], bfp[n_], acc[2 * (p) + m2][n_],                        \
        0, 0, 0, 0x7F7F7F7F, 0, 0x7F7F7F7F);                            \
  }                                                                     \
  __builtin_amdgcn_s_setprio(0);

#define DO_TILE(ktv, SA, SB, RDN, HASW, WV)                             \
  {                                                                     \
    READ_B2(BBUF((ktv) & 1), 2); READ_B2(BBUF((ktv) & 1), 3);           \
    MFMA_P(0);                                                          \
    READ_A2(ABUF((ktv) & 1), 1);                                        \
    if (SA) { SG_A(0, (ktv) + 1, smem + ABUF(((ktv) + 1) & 1));         \
              SG_A(1, (ktv) + 1, smem + ABUF(((ktv) + 1) & 1));         \
              SG_A(2, (ktv) + 1, smem + ABUF(((ktv) + 1) & 1));         \
              SG_A(3, (ktv) + 1, smem + ABUF(((ktv) + 1) & 1)); }       \
    BARRIER();   /* current-B reads complete before ph3 SG_B */         \
    MFMA_P(1);                                                          \
    READ_A2(ABUF((ktv) & 1), 2);                                        \
    MFMA_P(2);                                                          \
    READ_A2(ABUF((ktv) & 1), 3);                                        \
    if (SB) { SG_B(0, (ktv) + 2, smem + BBUF((ktv) & 1));               \
              SG_B(1, (ktv) + 2, smem + BBUF((ktv) & 1));               \
              SG_B(2, (ktv) + 2, smem + BBUF((ktv) & 1));               \
              SG_B(3, (ktv) + 2, smem + BBUF((ktv) & 1)); }             \
    if (HASW) { WAITV(WV); }                                            \
    BARRIER();   /* staged data visible for ph4 next-buffer reads */    \
    MFMA_P(3);                                                          \
    if (RDN) { READ_A2(ABUF(((ktv) + 1) & 1), 0);                       \
               READ_B2(BBUF(((ktv) + 1) & 1), 0);                       \
               READ_B2(BBUF(((ktv) + 1) & 1), 1); }                     \
  }

// -------- tail-path macros (MX-fp8, 64x128 tile, BK=128) --------
#define UABUF(c) ((c) ? 8192 : 0)
#define UBBUF(c) ((c) ? 32768 : 16384)

#define USG_A(ktv, dstoff) gload16(reps8 + (size_t)(uarow0 + (t >> 3)) * 1024 + \
                                       (ktv) * 128 + (((t & 7) ^ ((t >> 3) & 7)) << 4), \
                                   smem + (dstoff) + (size_t)t * 16)
#define USG_B(ii, ktv, dstoff) gload16(reps8 + (size_t)(ubrow0 + (ii) * 64 + (t >> 3)) * 1024 + \
                                       (ktv) * 128 + (((t & 7) ^ ((t >> 3) & 7)) << 4), \
                                   smem + (dstoff) + (size_t)(ii) * 8192 + (size_t)t * 16)

#define UREAD_A(bufoff) do {                                                          \
    i32x4 a0l = *(const i32x4*)(smem + (bufoff) + uarow * 128 + off0);                \
    i32x4 a0h = *(const i32x4*)(smem + (bufoff) + uarow * 128 + off1);                \
    i32x4 a1l = *(const i32x4*)(smem + (bufoff) + (uarow + 16) * 128 + off0);         \
    i32x4 a1h = *(const i32x4*)(smem + (bufoff) + (uarow + 16) * 128 + off1);         \
    ua[0] = __builtin_shufflevector(a0l, a0h, 0, 1, 2, 3, 4, 5, 6, 7);                \
    ua[1] = __builtin_shufflevector(a1l, a1h, 0, 1, 2, 3, 4, 5, 6, 7);                \
  } while (0)

#define UREAD_B(bufoff) do {                                                          \
    i32x4 b0l = *(const i32x4*)(smem + (bufoff) + ubrow * 128 + off0);                \
    i32x4 b0h = *(const i32x4*)(smem + (bufoff) + ubrow * 128 + off1);                \
    i32x4 b1l = *(const i32x4*)(smem + (bufoff) + (ubrow + 16) * 128 + off0);         \
    i32x4 b1h = *(const i32x4*)(smem + (bufoff) + (ubrow + 16) * 128 + off1);         \
    ub[0] = __builtin_shufflevector(b0l, b0h, 0, 1, 2, 3, 4, 5, 6, 7);                \
    ub[1] = __builtin_shufflevector(b1l, b1h, 0, 1, 2, 3, 4, 5, 6, 7);                \
  } while (0)

#define UMFMA(n)                                                        \
  __builtin_amdgcn_s_setprio(1);                                        \
  _Pragma("unroll") for (int m2 = 0; m2 < 2; m2++)                      \
    uacc[m2][n] = __builtin_amdgcn_mfma_scale_f32_16x16x128_f8f6f4(     \
        ua[m2], ub[n], uacc[m2][n], 0, 0, 0, 0x7F7F7F7F, 0, 0x7F7F7F7F);\
  __builtin_amdgcn_s_setprio(0);

#define UTILE(tv, S, R, HASW, WV)                                       \
  {                                                                     \
    UMFMA(0);                                                           \
    LGKM0();                                                            \
    BARRIER();                                                          \
    if (S) { USG_A((tv) + 2, UABUF((tv) & 1));                          \
             USG_B(0, (tv) + 2, UBBUF((tv) & 1));                       \
             USG_B(1, (tv) + 2, UBBUF((tv) & 1)); }                     \
    UMFMA(1);                                                           \
    if (HASW) { WAITV(WV); }                                            \
    BARRIER();                                                          \
    if (R) { UREAD_A(UABUF(((tv) + 1) & 1)); UREAD_B(UBBUF(((tv) + 1) & 1)); } \
  }

__global__ __launch_bounds__(512, 1) void kgemm3(const unsigned char* __restrict__ reps8,
                                                 float* __restrict__ partial) {
  extern __shared__ char smem[];
  const int t = threadIdx.x;
  const int l = t & 63, w = t >> 6;
  const int wr = w >> 2, wc = w & 3;          // 2 x 4 wave grid
  const int q2 = (l >> 4) & 3;
  const int r7 = l & 7;
  const int off0 = ((2 * q2) ^ r7) << 4;
  const int off1 = ((2 * q2 + 1) ^ r7) << 4;

  if (blockIdx.x < 128) {
    // ================= tail path: 64x128 eighth-tiles of tiles (0,16..31) =============
    const int b = (int)blockIdx.x;              // 0..127
    const int s = b >> 3, sub = b & 7;
    const int qr = sub >> 1;                    // 64-row chunk of rows 0..255
    const int qc = sub & 1;                     // 128-col half of the 256-col tile
    const int cbt = 16 + s;

    f32x4 uacc[2][2];
    const f32x4 zero4t = {0.f, 0.f, 0.f, 0.f};
#pragma unroll
    for (int m = 0; m < 2; m++)
#pragma unroll
      for (int n = 0; n < 2; n++) uacc[m][n] = zero4t;

    const size_t uarow0 = (size_t)qr * 64;
    const size_t ubrow0 = (size_t)cbt * 256 + (size_t)qc * 128;
    const int uarow = wr * 32 + (l & 15);
    const int ubrow = wc * 32 + (l & 15);

    USG_A(0, 0); USG_B(0, 0, 16384); USG_B(1, 0, 16384);
    USG_A(1, 8192); USG_B(0, 1, 32768); USG_B(1, 1, 32768);
    WAITV(3);
    BARRIER();

    i32x8 ua[2], ub[2];
    UREAD_A(0); UREAD_B(16384);

    UTILE(0, 1, 1, 1, 3)
    UTILE(1, 1, 1, 1, 3)
    UTILE(2, 1, 1, 1, 3)
    UTILE(3, 1, 1, 1, 3)
    UTILE(4, 1, 1, 1, 3)
    UTILE(5, 1, 1, 1, 3)
    UTILE(6, 0, 1, 1, 0)
    UTILE(7, 0, 0, 0, 0)

    float rsum[2][4];
    float csum[2];
#pragma unroll
    for (int m = 0; m < 2; m++)
#pragma unroll
      for (int j = 0; j < 4; j++) rsum[m][j] = 0.f;
    csum[0] = 0.f; csum[1] = 0.f;

#pragma unroll
    for (int m = 0; m < 2; m++)
#pragma unroll
      for (int n = 0; n < 2; n++)
#pragma unroll
        for (int j = 0; j < 4; j++) {
          const float e = exp2f(uacc[m][n][j] * EXPSCALE);
          rsum[m][j] += e;
          csum[n] += e;
        }
#pragma unroll
    for (int m = 0; m < 2; m++)
#pragma unroll
      for (int j = 0; j < 4; j++) {
        float v = rsum[m][j];
        v += __shfl_xor(v, 1); v += __shfl_xor(v, 2);
        v += __shfl_xor(v, 4); v += __shfl_xor(v, 8);
        rsum[m][j] = v;
      }
#pragma unroll
    for (int n = 0; n < 2; n++) {
      float v = csum[n];
      v += __shfl_xor(v, 16); v += __shfl_xor(v, 32);
      csum[n] = v;
    }

    const int col16 = l & 15, rgp = (l >> 4) & 3;
    float* rS = (float*)smem;            // [4 wc][64 rows]
    float* cS = ((float*)smem) + 256;    // [2 wr][128 cols]
    if (col16 == 0) {
#pragma unroll
      for (int m = 0; m < 2; m++)
#pragma unroll
        for (int j = 0; j < 4; j++)
          rS[wc * 64 + wr * 32 + m * 16 + rgp * 4 + j] = rsum[m][j];
    }
    if (rgp == 0) {
#pragma unroll
      for (int n = 0; n < 2; n++)
        cS[wr * 128 + wc * 32 + n * 16 + col16] = csum[n];
    }
    __syncthreads();
    if (t < 64) {
      const float rs = rS[t] + rS[64 + t] + rS[128 + t] + rS[192 + t];
      partial[(size_t)(cbt * 2 + qc) * N2 + qr * 64 + t] = rs;
    }
    if (t < 128) {
      const float cs = cS[t] + cS[128 + t];
      partial[(size_t)(64 + qr) * N2 + cbt * 256 + qc * 128 + t] = cs;
    }
    return;
  }

  // ================= main path: 256x256 MX-fp8 tiles =================================
  int bid = (int)blockIdx.x - 128;
  bid = (bid & 7) * 64 + (bid >> 3);   // XCD swizzle (512 = 8*64, bijective)
  int rb, cb;
  if (bid < 16) {
    rb = 0; cb = bid;
  } else {
    int rem = bid - 16;
    rb = 1;
    while (rem >= NTB - rb) { rem -= NTB - rb; rb++; }
    cb = rb + rem;
  }

  f32x4 acc[8][4];
  const f32x4 zero4 = {0.f, 0.f, 0.f, 0.f};
#pragma unroll
  for (int m = 0; m < 8; m++)
#pragma unroll
    for (int n = 0; n < 4; n++) acc[m][n] = zero4;

  const size_t arow0 = (size_t)rb * 256;
  const size_t brow0 = (size_t)cb * 256;

  const int arow = wr * 128 + (l & 15);
  const int brow = wc * 64 + (l & 15);
  const int aaddr0 = arow * 128 + off0;
  const int aaddr1 = arow * 128 + off1;
  const int baddr0 = brow * 128 + off0;
  const int baddr1 = brow * 128 + off1;

  // ---- prologue: B(0), A(0), B(1); retire B(0)+A(0); preload tile-0 ph1 ops ----
  SG_B(0, 0, smem + 32768); SG_B(1, 0, smem + 32768);
  SG_B(2, 0, smem + 32768); SG_B(3, 0, smem + 32768);
  SG_A(0, 0, smem); SG_A(1, 0, smem); SG_A(2, 0, smem); SG_A(3, 0, smem);
  SG_B(0, 1, smem + 49152); SG_B(1, 1, smem + 49152);
  SG_B(2, 1, smem + 49152); SG_B(3, 1, smem + 49152);
  WAITV(4);
  BARRIER();

  i32x8 afp[2], bfp[4];
  READ_A2(0, 0);
  READ_B2(32768, 0);
  READ_B2(32768, 1);

  DO_TILE(0, 1, 1, 1, 1, 4)
  DO_TILE(1, 1, 1, 1, 1, 4)
  DO_TILE(2, 1, 1, 1, 1, 4)
  DO_TILE(3, 1, 1, 1, 1, 4)
  DO_TILE(4, 1, 1, 1, 1, 4)
  DO_TILE(5, 1, 1, 1, 1, 4)
  DO_TILE(6, 1, 0, 1, 1, 0)
  DO_TILE(7, 0, 0, 0, 0, 0)

  // -------- epilogue: exp + diagonal mask + row/col partial sums --------
  float rsum[8][4];
  float csum[4];
#pragma unroll
  for (int m = 0; m < 8; m++)
#pragma unroll
    for (int j = 0; j < 4; j++) rsum[m][j] = 0.f;
#pragma unroll
  for (int n = 0; n < 4; n++) csum[n] = 0.f;

  const int col16 = l & 15, rgp = (l >> 4) & 3;
  const bool diag = (rb == cb);
  const int growbase = wr * 128 + rgp * 4;
  const int gcolbase = wc * 64 + col16;
#pragma unroll
  for (int m = 0; m < 8; m++) {
#pragma unroll
    for (int n = 0; n < 4; n++) {
#pragma unroll
      for (int j = 0; j < 4; j++) {
        const float e = (diag && (growbase + m * 16 + j) == (gcolbase + n * 16))
                            ? 0.f
                            : exp2f(acc[m][n][j] * EXPSCALE);
        rsum[m][j] += e;
        csum[n] += e;
      }
    }
  }
#pragma unroll
  for (int m = 0; m < 8; m++)
#pragma unroll
    for (int j = 0; j < 4; j++) {
      float v = rsum[m][j];
      v += __shfl_xor(v, 1); v += __shfl_xor(v, 2);
      v += __shfl_xor(v, 4); v += __shfl_xor(v, 8);
      rsum[m][j] = v;
    }
#pragma unroll
  for (int n = 0; n < 4; n++) {
    float v = csum[n];
    v += __shfl_xor(v, 16); v += __shfl_xor(v, 32);
    csum[n] = v;
  }

  __syncthreads();   // all waves done with LDS tiles before reuse as reduction scratch
  float* rS = (float*)smem;            // [4 wc][256 rows]
  float* cS = ((float*)smem) + 1024;   // [2 wr][256 cols]
  if (col16 == 0) {
#pragma unroll
    for (int m = 0; m < 8; m++)
#pragma unroll
      for (int j = 0; j < 4; j++)
        rS[wc * 256 + wr * 128 + m * 16 + rgp * 4 + j] = rsum[m][j];
  }
  if (rgp == 0) {
#pragma unroll
    for (int n = 0; n < 4; n++)
      cS[wr * 256 + wc * 64 + n * 16 + col16] = csum[n];
  }
  __syncthreads();
  // partial layout: [68 col-blocks of 128][8192 rows]
  if (t < 256) {
    const float rs_lo = rS[t] + rS[256 + t];
    const float rs_hi = rS[512 + t] + rS[768 + t];
    partial[(size_t)(cb * 2) * N2 + rb * 256 + t] = rs_lo;
    partial[(size_t)(cb * 2 + 1) * N2 + rb * 256 + t] = rs_hi;
    if (!diag) {
      partial[(size_t)(rb * 2) * N2 + cb * 256 + t] = cS[t];
      partial[(size_t)(rb * 2 + 1) * N2 + cb * 256 + t] = cS[256 + t];
    }
  }
}

// ---------------- Kernel C1: per-row denom; log; block sum --------------------------------
__device__ inline float blockReduce(float v, float* sred) {
#pragma unroll
  for (int o = 32; o > 0; o >>= 1) v += __shfl_xor(v, o);
  const int lane = threadIdx.x & 63, wid = threadIdx.x >> 6;
  if (lane == 0) sred[wid] = v;
  __syncthreads();
  v = sred[0] + sred[1] + sred[2] + sred[3];
  __syncthreads();
  return v;
}

__global__ __launch_bounds__(256) void kred1(const float* __restrict__ partial,
                                             float* __restrict__ bsum) {
  const int r = blockIdx.x * 256 + threadIdx.x;
  float d = 0.f;
#pragma unroll 8
  for (int cbx = 0; cbx < 64; ++cbx) d += partial[(size_t)cbx * N2 + r];
  if (blockIdx.x >= 16) {   // rows >= 4096: add tail colsum slots 64..67
#pragma unroll
    for (int cbx = 64; cbx < 68; ++cbx) d += partial[(size_t)cbx * N2 + r];
  }
  float v = logf(d);
  __shared__ float sred[4];
  v = blockReduce(v, sred);
  if (threadIdx.x == 0) bsum[blockIdx.x] = v;
}

// ---------------- Kernel C2: final scalar -------------------------------------------------
__global__ __launch_bounds__(256) void kred2(const float* __restrict__ bsum,
                                             const float* __restrict__ pos,
                                             float* __restrict__ out) {
  const int t = threadIdx.x;
  float v = (t < 32) ? bsum[t] : 0.f;
  float p = 0.f;
  for (int k = t; k < BSZ; k += 256) p += pos[k];
  __shared__ float sred[4];
  v = blockReduce(v, sred);
  p = blockReduce(p, sred);
  if (t == 0) out[0] = (v - 2.0f * p / TEMPV) / (float)N2;
}

extern "C" void kernel_launch(void* const* d_in, const int* in_sizes, int n_in,
                              void* d_out, int out_size, void* d_ws, size_t ws_size,
                              hipStream_t stream) {
  const float* ei = (const float*)d_in[0];
  const float* ej = (const float*)d_in[1];
  char* ws = (char*)d_ws;
  unsigned char* reps8 = (unsigned char*)ws;                           // 8 MB fp8 [8192][1024]
  float* partial = (float*)(ws + (size_t)8 * 1024 * 1024);             // 2.13 MB [68][8192]
  float* pos = (float*)(ws + (size_t)8 * 1024 * 1024 + 2304 * 1024);   // 16 KB [4096]
  float* bsum = (float*)(ws + (size_t)8 * 1024 * 1024 + 2304 * 1024 + 16384); // 128 B

  (void)hipFuncSetAttribute((const void*)kgemm3,
                            hipFuncAttributeMaxDynamicSharedMemorySize, 131072);

  knorm<<<BSZ / 4, 256, 0, stream>>>(ei, ej, reps8, pos);
  kgemm3<<<640, 512, 131072, stream>>>(reps8, partial);
  kred1<<<32, 256, 0, stream>>>(partial, bsum);
  kred2<<<1, 256, 0, stream>>>(bsum, pos, (float*)d_out);
}